// Round 9
// baseline (117.991 us; speedup 1.0000x reference)
//
#include <hip/hip_runtime.h>
#include <cmath>

// Local contrast normalization — barrier-free wave-streaming, v4 (compact code).
// r8 post-mortem: the 24-step fully-unrolled pipeline was ~60-70 KB of text,
// blowing the L1 I-cache -> ~6k cyc/step instruction-fetch stalls (VALUBusy
// 22%, occupancy-insensitive). Fix: ONE predicated 8-step body looped 3x
// (ring indices stay static), ~1/3 the code. Also 4 independent waves per
// 256-thread workgroup (adjacent strips, no barriers) -> 16 waves/CU.
//
// x: [64,512,512,1] f32; 9x9 Gaussian (separable, center 4.5), SAME zero pad;
// out = keep ? d/sqrt(conv(d^2)) : d, keep = sqrt(n2) > 0.5 <=> n2 > 0.25.
// One wave owns a full 512-px row: 8 px = 2 float4 per lane; strip = 8 rows.

struct W9 { float w[9]; };

#define HW    512
#define SROWS 8

__device__ __forceinline__ float4 f4scale(float s, float4 a) {
    return float4{s * a.x, s * a.y, s * a.z, s * a.w};
}
__device__ __forceinline__ float4 f4fma(float s, float4 a, float4 acc) {
    return float4{fmaf(s, a.x, acc.x), fmaf(s, a.y, acc.y),
                  fmaf(s, a.z, acc.z), fmaf(s, a.w, acc.w)};
}

// 9-tap conv over a 16-float window -> 8 outputs (o[k] = sum_j w[j]*X[k+j])
__device__ __forceinline__ void conv9_8(const float X[16], const float* w,
                                        float4& o0, float4& o1) {
    float o[8];
#pragma unroll
    for (int k = 0; k < 8; ++k) {
        float a = w[0] * X[k];
#pragma unroll
        for (int j = 1; j < 9; ++j) a = fmaf(w[j], X[k + j], a);
        o[k] = a;
    }
    o0 = float4{o[0], o[1], o[2], o[3]};
    o1 = float4{o[4], o[5], o[6], o[7]};
}

// vertical 9-tap from 8-deep ring + current row
#define VRING9(ring0, ring1, ppv, cur0, cur1, out0, out1)                \
    {                                                                    \
        out0 = f4scale(w[8], cur0);                                      \
        out1 = f4scale(w[8], cur1);                                      \
        _Pragma("unroll") for (int i_ = 0; i_ < 8; ++i_) {               \
            out0 = f4fma(w[i_], ring0[((ppv) + i_) & 7], out0);          \
            out1 = f4fma(w[i_], ring1[((ppv) + i_) & 7], out1);          \
        }                                                                \
    }

// stage A: hv = horizontal conv of x row r (zero outside image)
#define STAGE_A(r, hv0, hv1)                                             \
    {                                                                    \
        hv0 = z4; hv1 = z4;                                              \
        if ((unsigned)(r) < HW) {                                        \
            const float4* row_ =                                         \
                reinterpret_cast<const float4*>(xb + (size_t)(r) * HW);  \
            float4 a_ = pl ? row_[c2 - 1] : z4;                          \
            float4 b_ = row_[c2];                                        \
            float4 g_ = row_[c2 + 1];                                    \
            float4 e_ = pr ? row_[c2 + 2] : z4;                          \
            const float X_[16] = {a_.x, a_.y, a_.z, a_.w,                \
                                  b_.x, b_.y, b_.z, b_.w,                \
                                  g_.x, g_.y, g_.z, g_.w,                \
                                  e_.x, e_.y, e_.z, e_.w};               \
            conv9_8(X_, w, hv0, hv1);                                    \
        }                                                                \
    }

// stage B: mean(rd) = v-conv(hx ring + hv); d = x(rd) - mean (0 outside)
#define STAGE_B(ppv, rd, hv0, hv1, d0_, d1_)                             \
    {                                                                    \
        d0_ = z4; d1_ = z4;                                              \
        if ((unsigned)(rd) < HW) {                                       \
            float4 m0_, m1_;                                             \
            VRING9(hx0, hx1, ppv, hv0, hv1, m0_, m1_);                   \
            const float4* rowd_ =                                        \
                reinterpret_cast<const float4*>(xb + (size_t)(rd) * HW); \
            float4 x0_ = rowd_[c2], x1_ = rowd_[c2 + 1];                 \
            d0_ = float4{x0_.x - m0_.x, x0_.y - m0_.y,                   \
                         x0_.z - m0_.z, x0_.w - m0_.w};                  \
            d1_ = float4{x1_.x - m1_.x, x1_.y - m1_.y,                   \
                         x1_.z - m1_.z, x1_.w - m1_.w};                  \
        }                                                                \
    }

// stage C: h2v = h-conv(d^2); halo f4s via intra-wave shuffles
#define STAGE_C(d0_, d1_, h2v0, h2v1)                                    \
    {                                                                    \
        float4 dl_;                                                      \
        dl_.x = __shfl_up((d1_).x, 1);                                   \
        dl_.y = __shfl_up((d1_).y, 1);                                   \
        dl_.z = __shfl_up((d1_).z, 1);                                   \
        dl_.w = __shfl_up((d1_).w, 1);                                   \
        if (c == 0) dl_ = z4;                                            \
        float4 dr_;                                                      \
        dr_.x = __shfl_down((d0_).x, 1);                                 \
        dr_.y = __shfl_down((d0_).y, 1);                                 \
        dr_.z = __shfl_down((d0_).z, 1);                                 \
        dr_.w = __shfl_down((d0_).w, 1);                                 \
        if (c == 63) dr_ = z4;                                           \
        const float Xs_[16] = {                                          \
            dl_.x * dl_.x, dl_.y * dl_.y, dl_.z * dl_.z, dl_.w * dl_.w,  \
            (d0_).x * (d0_).x, (d0_).y * (d0_).y,                        \
            (d0_).z * (d0_).z, (d0_).w * (d0_).w,                        \
            (d1_).x * (d1_).x, (d1_).y * (d1_).y,                        \
            (d1_).z * (d1_).z, (d1_).w * (d1_).w,                        \
            dr_.x * dr_.x, dr_.y * dr_.y, dr_.z * dr_.z, dr_.w * dr_.w}; \
        conv9_8(Xs_, w, h2v0, h2v1);                                     \
    }

__global__ __launch_bounds__(256, 2) void lcn_kernel(const float* __restrict__ x,
                                                     float* __restrict__ out,
                                                     W9 wts) {
    const int tid = threadIdx.x;
    const int c = tid & 63;             // lane, owns f4 cols 2c, 2c+1
    const int c2 = 2 * c;
    const int wv = tid >> 6;            // wave 0..3 within workgroup
    const bool pl = (c > 0), pr = (c < 63);

    // XCD swizzle: 1024 wg = 8 XCDs x 128; global wave id g covers
    // 64 images x 64 strips; the 4 waves of a wg take ADJACENT strips
    // (shared halo rows -> L1/L2 locality); 8 images per XCD.
    const int p = blockIdx.x;                   // 0..1023
    const int lid = (p & 7) * 128 + (p >> 3);   // bijective
    const int g = lid * 4 + wv;                 // 0..4095
    const int img = g >> 6;                     // 0..63
    const int strip = g & 63;                   // 0..63
    const int R0 = strip * SROWS;

    const float* xb = x + (size_t)img * HW * HW;
    float* ob = out + (size_t)img * HW * HW;

    float w[9];
#pragma unroll
    for (int i = 0; i < 9; ++i) w[i] = wts.w[i];
    const float4 z4 = {0.f, 0.f, 0.f, 0.f};

    float4 hx0[8], hx1[8];   // h-conv(x) ring
    float4 q0[8], q1[8];     // h-conv(d^2) ring
    float4 dg0[4], dg1[4];   // d ring (4-step delay to output row)
#pragma unroll
    for (int i = 0; i < 8; ++i) { q0[i] = z4; q1[i] = z4; }
#pragma unroll
    for (int i = 0; i < 4; ++i) { dg0[i] = z4; dg1[i] = z4; }

    // 24 steps = 3 passes of ONE 8-step body (ring indices static);
    // wave-uniform predicates select the pipeline phase.
#pragma unroll 1
    for (int base = 0; base < 24; base += 8) {
        const bool doB = (base >= 8);
        const bool doD = (base >= 16);
#pragma unroll
        for (int pp = 0; pp < 8; ++pp) {
            const int r = R0 - 8 + base + pp;   // row loaded this step
            float4 hv0, hv1;
            STAGE_A(r, hv0, hv1);
            if (doB) {
                float4 d0, d1;
                STAGE_B(pp, r - 4, hv0, hv1, d0, d1);
                // read d(ro) (written 4 steps ago) BEFORE overwriting
                float4 do0 = dg0[pp & 3], do1 = dg1[pp & 3];
                dg0[pp & 3] = d0; dg1[pp & 3] = d1;
                hx0[pp] = hv0; hx1[pp] = hv1;   // after B consumed old slot
                float4 h2v0, h2v1;
                STAGE_C(d0, d1, h2v0, h2v1);
                if (doD) {
                    float4 n0, n1;
                    VRING9(q0, q1, pp, h2v0, h2v1, n0, n1);
                    const int ro = r - 8;       // in [R0, R0+8)
                    float4 o0, o1;
                    o0.x = (n0.x > 0.25f) ? do0.x * rsqrtf(n0.x) : do0.x;
                    o0.y = (n0.y > 0.25f) ? do0.y * rsqrtf(n0.y) : do0.y;
                    o0.z = (n0.z > 0.25f) ? do0.z * rsqrtf(n0.z) : do0.z;
                    o0.w = (n0.w > 0.25f) ? do0.w * rsqrtf(n0.w) : do0.w;
                    o1.x = (n1.x > 0.25f) ? do1.x * rsqrtf(n1.x) : do1.x;
                    o1.y = (n1.y > 0.25f) ? do1.y * rsqrtf(n1.y) : do1.y;
                    o1.z = (n1.z > 0.25f) ? do1.z * rsqrtf(n1.z) : do1.z;
                    o1.w = (n1.w > 0.25f) ? do1.w * rsqrtf(n1.w) : do1.w;
                    float4* rowo =
                        reinterpret_cast<float4*>(ob + (size_t)ro * HW);
                    rowo[c2] = o0;
                    rowo[c2 + 1] = o1;
                }
                q0[pp] = h2v0; q1[pp] = h2v1;
            } else {
                hx0[pp] = hv0; hx1[pp] = hv1;
            }
        }
    }
}

static W9 make_w() {
    // reference: sigmah = 9/6, exponent divides by 2*sigmah = 3.0;
    // taps centered at 4.5 (asymmetric); separable: w1 = g1 / sum(g1).
    double g[9], sum = 0.0;
    for (int i = 0; i < 9; ++i) {
        double off = (double)i - 4.5;
        g[i] = exp(-(off * off) / 3.0);
        sum += g[i];
    }
    W9 r;
    for (int i = 0; i < 9; ++i) r.w[i] = (float)(g[i] / sum);
    return r;
}

extern "C" void kernel_launch(void* const* d_in, const int* in_sizes, int n_in,
                              void* d_out, int out_size, void* d_ws, size_t ws_size,
                              hipStream_t stream) {
    const float* x = (const float*)d_in[0];
    float* out = (float*)d_out;
    W9 w = make_w();
    // 1024 workgroups x 256 threads; each wg = 4 independent waves on
    // adjacent 8-row strips (64 images x 64 strips total).
    lcn_kernel<<<dim3(1024), dim3(256), 0, stream>>>(x, out, w);
}

// Round 11
// 56.214 us; speedup vs baseline: 2.0989x; 2.0989x over previous
//
#include <hip/hip_runtime.h>
#include <cmath>

// Local contrast normalization, fused tile kernel (r3 structure, rebalanced).
// x: [64,512,512,1] f32. 9x9 Gaussian (separable, center 4.5), SAME zero pad.
// Tile: 64 wide x 32 tall, 256 threads. Contiguous LDS buffers (stride==width)
// => every b128 op has 16 consecutive lanes on 16 consecutive float4s.
// vs r3: p2 180 threads (was 144), p4 256 threads (was 128) — idle-wave
// reduction at the barriers; nontemporal output store (via ext_vector type,
// HIP_vector_type<float,4>* is rejected by the builtin).

struct W9 { float w[9]; };

typedef float nf4 __attribute__((ext_vector_type(4)));  // for nontemporal store

#define HW   512
#define HW4  128   // f4 per image row
#define TSY  32    // output tile height
#define NH1  18    // h1/dd width in f4 (72 cols: ox-4 .. ox+67)
#define NH2  16    // h2/out width in f4 (64 cols)
#define RH1  48    // h1 rows  (oy-8 .. oy+39)
#define RDD  40    // dd/h2 rows (oy-4 .. oy+35)

__device__ __forceinline__ float4 conv9(const float* X, const float* w) {
    float4 o = {0.f, 0.f, 0.f, 0.f};
#pragma unroll
    for (int j = 0; j < 9; ++j) {
        o.x = fmaf(w[j], X[j + 0], o.x);
        o.y = fmaf(w[j], X[j + 1], o.y);
        o.z = fmaf(w[j], X[j + 2], o.z);
        o.w = fmaf(w[j], X[j + 3], o.w);
    }
    return o;
}

__global__ __launch_bounds__(256, 6) void lcn_kernel(const float* __restrict__ x,
                                                     float* __restrict__ out,
                                                     W9 wts) {
    __shared__ float4 sm[RH1 * NH1 + RDD * NH1];  // 864 + 720 f4 = 25,344 B
    float4* h1 = sm;                 // [48][18]
    float4* dd = sm + RH1 * NH1;     // [40][18]
    float4* h2 = sm;                 // [40][16], aliases h1 (dead after p2)

    const int tid = threadIdx.x;
    const int oxf = blockIdx.x * NH2;        // f4 col of output tile
    const int oy  = blockIdx.y * TSY;
    const float* xb = x + (size_t)blockIdx.z * HW * HW;
    float* ob = out + (size_t)blockIdx.z * HW * HW;

    float w[9];
#pragma unroll
    for (int i = 0; i < 9; ++i) w[i] = wts.w[i];

    // ---- p1: h1[r][m] = h-conv(x) at row oy-8+r, f4 col oxf-1+m ----
    for (int o = tid; o < RH1 * NH1; o += 256) {
        int r = o / NH1, m = o % NH1;
        int gy = oy - 8 + r;
        float4 o4 = {0.f, 0.f, 0.f, 0.f};
        if (gy >= 0 && gy < HW) {
            const float4* row = reinterpret_cast<const float4*>(xb + (size_t)gy * HW);
            float X[12];
#pragma unroll
            for (int k = 0; k < 3; ++k) {
                int g4 = oxf - 2 + m + k;
                float4 v = (g4 >= 0 && g4 < HW4) ? row[g4] : float4{0.f, 0.f, 0.f, 0.f};
                X[4 * k + 0] = v.x; X[4 * k + 1] = v.y;
                X[4 * k + 2] = v.z; X[4 * k + 3] = v.w;
            }
            o4 = conv9(X, w);
        }
        h1[o] = o4;
    }
    __syncthreads();

    // ---- p2: mean = v-conv(h1); dd = x - mean (zero outside image) ----
    // 180 threads: f4-col m (18) x 10 row-groups of 4; 9-deep register ring.
    if (tid < 180) {
        int m = tid % NH1, rg = tid / NH1;   // rg 0..9
        int r0 = rg * 4;
        int g4 = oxf - 1 + m;
        bool cin = (g4 >= 0 && g4 < HW4);
        float4 ring[9];
#pragma unroll
        for (int i = 0; i < 9; ++i) ring[i] = h1[(r0 + i) * NH1 + m];
#pragma unroll
        for (int k = 0; k < 4; ++k) {
            if (k) ring[(k + 8) % 9] = h1[(r0 + 8 + k) * NH1 + m];
            float4 mean = {0.f, 0.f, 0.f, 0.f};
#pragma unroll
            for (int j = 0; j < 9; ++j) {
                const float4 h = ring[(k + j) % 9];
                mean.x = fmaf(w[j], h.x, mean.x);
                mean.y = fmaf(w[j], h.y, mean.y);
                mean.z = fmaf(w[j], h.z, mean.z);
                mean.w = fmaf(w[j], h.w, mean.w);
            }
            int rp = r0 + k;
            int gy = oy - 4 + rp;
            float4 d = {0.f, 0.f, 0.f, 0.f};
            if (cin && gy >= 0 && gy < HW) {
                float4 xv = reinterpret_cast<const float4*>(xb + (size_t)gy * HW)[g4];
                d.x = xv.x - mean.x; d.y = xv.y - mean.y;
                d.z = xv.z - mean.z; d.w = xv.w - mean.w;
            }
            dd[rp * NH1 + m] = d;
        }
    }
    __syncthreads();

    // ---- p3: h2[r][n] = h-conv(dd^2), 40 rows x 16 f4 ----
    for (int o = tid; o < RDD * NH2; o += 256) {
        int r = o / NH2, n = o % NH2;
        float4 a = dd[r * NH1 + n];
        float4 b = dd[r * NH1 + n + 1];
        float4 c = dd[r * NH1 + n + 2];
        float X[12] = {a.x * a.x, a.y * a.y, a.z * a.z, a.w * a.w,
                       b.x * b.x, b.y * b.y, b.z * b.z, b.w * b.w,
                       c.x * c.x, c.y * c.y, c.z * c.z, c.w * c.w};
        h2[o] = conv9(X, w);   // o == r*16 + n, contiguous
    }
    __syncthreads();

    // ---- p4: n2 = v-conv(h2); out = keep ? dd/sqrt(n2) : dd ----
    // 256 threads: f4-col n (16) x 16 row-groups of 2; register ring.
    {
        int n = tid % NH2, rg = tid / NH2;   // rg 0..15
        int r0 = rg * 2;
        float4 ring[9];
#pragma unroll
        for (int i = 0; i < 9; ++i) ring[i] = h2[(r0 + i) * NH2 + n];
#pragma unroll
        for (int k = 0; k < 2; ++k) {
            if (k) ring[(k + 8) % 9] = h2[(r0 + 8 + k) * NH2 + n];
            float4 n2 = {0.f, 0.f, 0.f, 0.f};
#pragma unroll
            for (int j = 0; j < 9; ++j) {
                const float4 h = ring[(k + j) % 9];
                n2.x = fmaf(w[j], h.x, n2.x);
                n2.y = fmaf(w[j], h.y, n2.y);
                n2.z = fmaf(w[j], h.z, n2.z);
                n2.w = fmaf(w[j], h.w, n2.w);
            }
            float4 dv = dd[(r0 + k + 4) * NH1 + n + 1];
            nf4 o;  // keep <=> sqrt(n2) > 0.5 <=> n2 > 0.25
            { float nr = rsqrtf(n2.x); o.x = (n2.x > 0.25f) ? dv.x * nr : dv.x; }
            { float nr = rsqrtf(n2.y); o.y = (n2.y > 0.25f) ? dv.y * nr : dv.y; }
            { float nr = rsqrtf(n2.z); o.z = (n2.z > 0.25f) ? dv.z * nr : dv.z; }
            { float nr = rsqrtf(n2.w); o.w = (n2.w > 0.25f) ? dv.w * nr : dv.w; }
            __builtin_nontemporal_store(o,
                reinterpret_cast<nf4*>(ob + (size_t)(oy + r0 + k) * HW) + oxf + n);
        }
    }
}

static W9 make_w() {
    // reference: sigmah = 9/6, exponent divides by 2*sigmah = 3.0;
    // taps centered at 4.5 (asymmetric); separable: w1 = g1 / sum(g1).
    double g[9], s = 0.0;
    for (int i = 0; i < 9; ++i) {
        double off = (double)i - 4.5;
        g[i] = exp(-(off * off) / 3.0);
        s += g[i];
    }
    W9 r;
    for (int i = 0; i < 9; ++i) r.w[i] = (float)(g[i] / s);
    return r;
}

extern "C" void kernel_launch(void* const* d_in, const int* in_sizes, int n_in,
                              void* d_out, int out_size, void* d_ws, size_t ws_size,
                              hipStream_t stream) {
    const float* x = (const float*)d_in[0];
    float* out = (float*)d_out;
    W9 w = make_w();
    dim3 grid(HW / 64, HW / TSY, 64);  // 8 x 16 x 64
    lcn_kernel<<<grid, dim3(256), 0, stream>>>(x, out, w);
}